// Round 1
// baseline (222.690 us; speedup 1.0000x reference)
//
#include <hip/hip_runtime.h>

#define B_SZ  32
#define IN_D  2048
#define OUT_D 2048
#define K_N   8
#define H_D   512
#define NPART 64

// ---------------------------------------------------------------------------
// K1a: partial[m][j] = sum_{i in stripe m} cond[i] * w1[i][j]
// 64 blocks x 256 threads; each block handles 32 rows of w1 (coalesced).
// ---------------------------------------------------------------------------
__global__ void k1_partial(const float* __restrict__ cond,
                           const float* __restrict__ w1,
                           float* __restrict__ ws) {
    const int m   = blockIdx.x;
    const int tid = threadIdx.x;
    const int ibase = m * (IN_D / NPART);
    float p0 = 0.f, p1 = 0.f;
    for (int ii = 0; ii < IN_D / NPART; ++ii) {
        const float c = cond[ibase + ii];
        const float* row = w1 + (size_t)(ibase + ii) * H_D;
        p0 = fmaf(c, row[tid], p0);
        p1 = fmaf(c, row[tid + 256], p1);
    }
    float* part = ws + 1024;
    part[(size_t)m * H_D + tid]       = p0;
    part[(size_t)m * H_D + tid + 256] = p1;
}

// ---------------------------------------------------------------------------
// K1b: h = relu(b1 + sum_m partial[m]); scores = h @ w2 + b2; softmax -> ws[0..7]
// 1 block x 512 threads.
// ---------------------------------------------------------------------------
__global__ void k1_scores(const float* __restrict__ b1,
                          const float* __restrict__ w2,
                          const float* __restrict__ b2,
                          float* __restrict__ ws) {
    __shared__ float hsh[H_D];
    const int tid = threadIdx.x;
    const float* part = ws + 1024;
    float acc = b1[tid];
    for (int m = 0; m < NPART; ++m) acc += part[(size_t)m * H_D + tid];
    hsh[tid] = fmaxf(acc, 0.f);
    __syncthreads();
    if (tid < 64) {
        float s[K_N];
        #pragma unroll
        for (int k = 0; k < K_N; ++k) s[k] = 0.f;
        #pragma unroll
        for (int jj = 0; jj < H_D / 64; ++jj) {
            const int j = jj * 64 + tid;
            const float hv = hsh[j];
            const float* wr = w2 + (size_t)j * K_N;
            #pragma unroll
            for (int k = 0; k < K_N; ++k) s[k] = fmaf(hv, wr[k], s[k]);
        }
        #pragma unroll
        for (int k = 0; k < K_N; ++k) {
            #pragma unroll
            for (int d = 1; d < 64; d <<= 1) s[k] += __shfl_xor(s[k], d, 64);
        }
        if (tid == 0) {
            float mx = -1e30f;
            #pragma unroll
            for (int k = 0; k < K_N; ++k) { s[k] += b2[k]; mx = fmaxf(mx, s[k]); }
            float sum = 0.f;
            #pragma unroll
            for (int k = 0; k < K_N; ++k) { s[k] = __expf(s[k] - mx); sum += s[k]; }
            const float inv = 1.f / sum;
            #pragma unroll
            for (int k = 0; k < K_N; ++k) ws[k] = s[k] * inv;
        }
    }
}

// ---------------------------------------------------------------------------
// K2: main. Each block owns 2 output columns o0,o0+1. Thread t owns
// i in [8t, 8t+8). Aggregate the 8 expert weights in registers (weights
// read exactly once from HBM, coalesced float4), FMA against x (L2-hot),
// then LDS two-sweep reduction over the 256 threads.
// ---------------------------------------------------------------------------
__global__ __launch_bounds__(256, 4) void k2_main(
    const float* __restrict__ x,
    const float* __restrict__ kw,
    const float* __restrict__ kb,
    const float* __restrict__ ws,
    float* __restrict__ out) {
    __shared__ float red[B_SZ][257];   // [batch][thread], +1 pad: conflict-free
    __shared__ float fin[8][B_SZ];
    const int tid = threadIdx.x;
    const int o0  = blockIdx.x * 2;
    const int i0  = tid * 8;

    float a[K_N];
    #pragma unroll
    for (int k = 0; k < K_N; ++k) a[k] = ws[k];

    // Aggregate weights for the 8-element i-chunk, both output columns.
    float wa[8], wb[8];
    #pragma unroll
    for (int j = 0; j < 8; ++j) { wa[j] = 0.f; wb[j] = 0.f; }
    #pragma unroll
    for (int k = 0; k < K_N; ++k) {
        const float* p = kw + ((size_t)k * OUT_D + o0) * IN_D + i0;
        float wv[8], wv2[8];
        *(float4*)&wv[0]  = *(const float4*)(p);
        *(float4*)&wv[4]  = *(const float4*)(p + 4);
        *(float4*)&wv2[0] = *(const float4*)(p + IN_D);
        *(float4*)&wv2[4] = *(const float4*)(p + IN_D + 4);
        const float ak = a[k];
        #pragma unroll
        for (int j = 0; j < 8; ++j) {
            wa[j] = fmaf(ak, wv[j],  wa[j]);
            wb[j] = fmaf(ak, wv2[j], wb[j]);
        }
    }

    // Dot with x for all 32 batches.
    float acc0[B_SZ], acc1[B_SZ];
    #pragma unroll
    for (int b = 0; b < B_SZ; ++b) {
        const float* xp = x + (size_t)b * IN_D + i0;
        float xv[8];
        *(float4*)&xv[0] = *(const float4*)(xp);
        *(float4*)&xv[4] = *(const float4*)(xp + 4);
        float s0 = 0.f, s1 = 0.f;
        #pragma unroll
        for (int j = 0; j < 8; ++j) {
            s0 = fmaf(wa[j], xv[j], s0);
            s1 = fmaf(wb[j], xv[j], s1);
        }
        acc0[b] = s0; acc1[b] = s1;
    }

    const int r = tid >> 5;   // 0..7
    const int b = tid & 31;

    // ---- sweep 0: reduce acc0 over 256 threads -> out[:, o0] ----
    #pragma unroll
    for (int j = 0; j < B_SZ; ++j) red[j][tid] = acc0[j];
    __syncthreads();
    {
        float s = 0.f;
        #pragma unroll
        for (int c = 0; c < 32; ++c) s += red[b][r * 32 + c];
        fin[r][b] = s;
    }
    __syncthreads();
    if (tid < B_SZ) {
        float tot = 0.f;
        #pragma unroll
        for (int rr = 0; rr < 8; ++rr) tot += fin[rr][tid];
        float aggb = 0.f;
        #pragma unroll
        for (int k = 0; k < K_N; ++k) aggb = fmaf(a[k], kb[(size_t)k * OUT_D + o0], aggb);
        out[(size_t)tid * OUT_D + o0] = tot + aggb;
    }
    __syncthreads();

    // ---- sweep 1: reduce acc1 -> out[:, o0+1] ----
    #pragma unroll
    for (int j = 0; j < B_SZ; ++j) red[j][tid] = acc1[j];
    __syncthreads();
    {
        float s = 0.f;
        #pragma unroll
        for (int c = 0; c < 32; ++c) s += red[b][r * 32 + c];
        fin[r][b] = s;
    }
    __syncthreads();
    if (tid < B_SZ) {
        float tot = 0.f;
        #pragma unroll
        for (int rr = 0; rr < 8; ++rr) tot += fin[rr][tid];
        float aggb = 0.f;
        #pragma unroll
        for (int k = 0; k < K_N; ++k) aggb = fmaf(a[k], kb[(size_t)k * OUT_D + o0 + 1], aggb);
        out[(size_t)tid * OUT_D + o0 + 1] = tot + aggb;
    }
}

extern "C" void kernel_launch(void* const* d_in, const int* in_sizes, int n_in,
                              void* d_out, int out_size, void* d_ws, size_t ws_size,
                              hipStream_t stream) {
    (void)in_sizes; (void)n_in; (void)out_size; (void)ws_size;
    const float* x    = (const float*)d_in[0];
    const float* cond = (const float*)d_in[1];
    const float* w1   = (const float*)d_in[2];
    const float* b1   = (const float*)d_in[3];
    const float* w2   = (const float*)d_in[4];
    const float* b2   = (const float*)d_in[5];
    const float* kw   = (const float*)d_in[6];
    const float* kb   = (const float*)d_in[7];
    float* out = (float*)d_out;
    float* ws  = (float*)d_ws;

    k1_partial<<<NPART, 256, 0, stream>>>(cond, w1, ws);
    k1_scores<<<1, H_D, 0, stream>>>(b1, w2, b2, ws);
    k2_main<<<OUT_D / 2, 256, 0, stream>>>(x, kw, kb, ws, out);
}